// Round 5
// baseline (1632.261 us; speedup 1.0000x reference)
//
#include <hip/hip_runtime.h>

#define F_IN 256
#define HID 16
#define NCLS 8
#define BSHIFT 11
#define BMASK ((1u << BSHIFT) - 1u)
#define NPB (1 << BSHIFT)       // nodes per bin = 2048
#define MAXBINS 64
#define BCAP 73728u             // per-bin edge capacity (mean ~65306, +33 sigma)
#define TILE 4096
#define WIN 32

typedef float f4v __attribute__((ext_vector_type(4)));

// ---------- init per-bin cursors --------------------------------------------
__global__ void k_bininit(unsigned* __restrict__ binCur) {
    if (threadIdx.x < MAXBINS) binCur[threadIdx.x] = threadIdx.x * BCAP;
}

// ---------- pass A: degree histogram + dst-binned edge buffer ----------------
// Writes per (block,bin) are contiguous runs -> no write amplification.
__global__ void __launch_bounds__(256) k_binA(const int* __restrict__ src,
                                              const int* __restrict__ dst, int e,
                                              unsigned* __restrict__ degc,
                                              unsigned* __restrict__ binCur,
                                              unsigned* __restrict__ binbuf) {
    __shared__ unsigned scnt[MAXBINS], lbase[MAXBINS], gbase[MAXBINS];
    __shared__ unsigned sbuf[TILE];
    __shared__ unsigned char sbin[TILE];
    int t = threadIdx.x;
    if (t < MAXBINS) scnt[t] = 0u;
    __syncthreads();
    int base = blockIdx.x * TILE;
    unsigned ent[16], rank[16];
    int ebin[16];
#pragma unroll
    for (int i = 0; i < 16; ++i) {
        int j = base + t + i * 256;
        ebin[i] = -1;
        if (j < e) {
            int d = __builtin_nontemporal_load(&dst[j]);
            int s = __builtin_nontemporal_load(&src[j]);
            atomicAdd(&degc[d], 1u);
            ent[i] = ((unsigned)s << BSHIFT) | ((unsigned)d & BMASK);
            ebin[i] = d >> BSHIFT;
            rank[i] = atomicAdd(&scnt[ebin[i]], 1u);
        }
    }
    __syncthreads();
    if (t == 0) {
        unsigned run = 0;
        for (int b = 0; b < MAXBINS; ++b) { lbase[b] = run; run += scnt[b]; }
    }
    __syncthreads();
    if (t < MAXBINS && scnt[t] > 0u) gbase[t] = atomicAdd(&binCur[t], scnt[t]);
    __syncthreads();
#pragma unroll
    for (int i = 0; i < 16; ++i)
        if (ebin[i] >= 0) {
            unsigned p = lbase[ebin[i]] + rank[i];
            sbuf[p] = ent[i];
            sbin[p] = (unsigned char)ebin[i];
        }
    __syncthreads();
    int total = e - base; if (total > TILE) total = TILE;
    for (int idx = t; idx < total; idx += 256) {
        int b = sbin[idx];
        __builtin_nontemporal_store(sbuf[idx], &binbuf[gbase[b] + ((unsigned)idx - lbase[b])]);
    }
}

// ---------- dinv -------------------------------------------------------------
__global__ void k_dinv(const unsigned* __restrict__ cnt, float* __restrict__ dinv, int n) {
    int i = blockIdx.x * blockDim.x + threadIdx.x;
    if (i < n) dinv[i] = rsqrtf((float)(cnt[i] + 1u));
}

// ---------- GEMM1: t1w[n,16] = (x @ W1) * dinv[row] --------------------------
__global__ void __launch_bounds__(256) k_gemm1(const float* __restrict__ x,
                                               const float* __restrict__ W1,
                                               const float* __restrict__ dinv,
                                               float* __restrict__ t1w, int n) {
    __shared__ float ws[HID][260];
    for (int idx = threadIdx.x; idx < F_IN * HID; idx += 256) {
        int c = idx >> 4, k = idx & 15;
        ws[k][c] = W1[idx];
    }
    __syncthreads();
    int r = blockIdx.x * 16 + (threadIdx.x >> 4);
    int k = threadIdx.x & 15;
    if (r >= n) return;
    const f4v* xr = (const f4v*)(x + (size_t)r * F_IN);
    const f4v* wr = (const f4v*)&ws[k][0];
    float acc = 0.f;
#pragma unroll 8
    for (int c4 = 0; c4 < F_IN / 4; ++c4) {
        f4v v = __builtin_nontemporal_load(&xr[c4]);
        f4v w = wr[c4];
        acc += v[0] * w[0] + v[1] * w[1] + v[2] * w[2] + v[3] * w[3];
    }
    t1w[(size_t)r * HID + k] = acc * dinv[r];
}

// ---------- conv1 aggregation: LDS scatter-add per bin, 8 feats per block ----
__global__ void __launch_bounds__(512) k_agg1(const unsigned* __restrict__ binbuf,
                                              const unsigned* __restrict__ binCur,
                                              const float* __restrict__ t1w,
                                              const float* __restrict__ dinv,
                                              const float* __restrict__ b1,
                                              float* __restrict__ h, int n) {
    __shared__ f4v accv[NPB * 8 / 4];  // 64 KB
    float* acc = (float*)accv;
    int t = threadIdx.x;
    int b = blockIdx.x, f0 = blockIdx.y * 8;
    f4v z = {0.f, 0.f, 0.f, 0.f};
    for (int i = t; i < NPB * 8 / 4; i += 512) accv[i] = z;
    __syncthreads();
    unsigned jb = (unsigned)b * BCAP, je = binCur[b];
    int k = t & 7;
    unsigned j = jb + (t >> 3);
    for (; j + 64 < je; j += 128) {
        unsigned v0 = __builtin_nontemporal_load(&binbuf[j]);
        unsigned v1 = __builtin_nontemporal_load(&binbuf[j + 64]);
        float a0 = t1w[(size_t)(v0 >> BSHIFT) * HID + f0 + k];
        float a1 = t1w[(size_t)(v1 >> BSHIFT) * HID + f0 + k];
        atomicAdd(&acc[(v0 & BMASK) * 8 + k], a0);
        atomicAdd(&acc[(v1 & BMASK) * 8 + k], a1);
    }
    for (; j < je; j += 64) {
        unsigned v = __builtin_nontemporal_load(&binbuf[j]);
        float a = t1w[(size_t)(v >> BSHIFT) * HID + f0 + k];
        atomicAdd(&acc[(v & BMASK) * 8 + k], a);
    }
    __syncthreads();
    int dbase = b << BSHIFT;
    for (int idx = t; idx < NPB * 8; idx += 512) {
        int dl = idx >> 3, kk = idx & 7;
        int d = dbase + dl;
        if (d < n) {
            float self = t1w[(size_t)d * HID + f0 + kk];
            h[(size_t)d * HID + f0 + kk] =
                fmaxf(dinv[d] * (acc[idx] + self) + b1[f0 + kk], 0.f);
        }
    }
}

// ---------- GEMM2: t2w[n,8] = (h @ W2) * dinv[row] ---------------------------
__global__ void __launch_bounds__(256) k_gemm2(const float* __restrict__ h,
                                               const float* __restrict__ W2,
                                               const float* __restrict__ dinv,
                                               float* __restrict__ t2w, int n) {
    __shared__ float w2s[HID * NCLS];
    if (threadIdx.x < HID * NCLS) w2s[threadIdx.x] = W2[threadIdx.x];
    __syncthreads();
    int i = blockIdx.x * blockDim.x + threadIdx.x;
    if (i >= n) return;
    float hv[HID];
    const f4v* h4 = (const f4v*)(h + (size_t)i * HID);
#pragma unroll
    for (int q = 0; q < 4; ++q) {
        f4v v = h4[q];
        hv[q * 4 + 0] = v[0]; hv[q * 4 + 1] = v[1];
        hv[q * 4 + 2] = v[2]; hv[q * 4 + 3] = v[3];
    }
    float o[NCLS];
#pragma unroll
    for (int c = 0; c < NCLS; ++c) o[c] = 0.f;
#pragma unroll
    for (int k = 0; k < HID; ++k)
#pragma unroll
        for (int c = 0; c < NCLS; ++c) o[c] += hv[k] * w2s[k * NCLS + c];
    float di = dinv[i];
    f4v* o4 = (f4v*)(t2w + (size_t)i * NCLS);
    f4v r0 = {o[0] * di, o[1] * di, o[2] * di, o[3] * di};
    f4v r1 = {o[4] * di, o[5] * di, o[6] * di, o[7] * di};
    o4[0] = r0;
    o4[1] = r1;
}

// ---------- conv2 aggregation (LDS scatter-add) + bias + fused mean-pool -----
__global__ void __launch_bounds__(512) k_agg2pool(const unsigned* __restrict__ binbuf,
                                                  const unsigned* __restrict__ binCur,
                                                  const float* __restrict__ t2w,
                                                  const float* __restrict__ dinv,
                                                  const float* __restrict__ b2,
                                                  const int* __restrict__ batch,
                                                  float* __restrict__ out,
                                                  float* __restrict__ cg, int n) {
    __shared__ f4v accv[NPB * NCLS / 4];  // 64 KB
    float* acc = (float*)accv;
    __shared__ float wacc[WIN * NCLS];
    __shared__ float wcnt[WIN];
    __shared__ int gbase_s;
    int t = threadIdx.x;
    int b = blockIdx.x;
    int dbase = b << BSHIFT;
    f4v z = {0.f, 0.f, 0.f, 0.f};
    for (int i = t; i < NPB * NCLS / 4; i += 512) accv[i] = z;
    if (t < WIN * NCLS) wacc[t] = 0.f;
    if (t < WIN) wcnt[t] = 0.f;
    if (t == 0) gbase_s = batch[dbase < n ? dbase : (n - 1)];
    __syncthreads();
    unsigned jb = (unsigned)b * BCAP, je = binCur[b];
    int k = t & 7;
    unsigned j = jb + (t >> 3);
    for (; j + 64 < je; j += 128) {
        unsigned v0 = __builtin_nontemporal_load(&binbuf[j]);
        unsigned v1 = __builtin_nontemporal_load(&binbuf[j + 64]);
        float a0 = t2w[(size_t)(v0 >> BSHIFT) * NCLS + k];
        float a1 = t2w[(size_t)(v1 >> BSHIFT) * NCLS + k];
        atomicAdd(&acc[(v0 & BMASK) * 8 + k], a0);
        atomicAdd(&acc[(v1 & BMASK) * 8 + k], a1);
    }
    for (; j < je; j += 64) {
        unsigned v = __builtin_nontemporal_load(&binbuf[j]);
        float a = t2w[(size_t)(v >> BSHIFT) * NCLS + k];
        atomicAdd(&acc[(v & BMASK) * 8 + k], a);
    }
    __syncthreads();
    int gb = gbase_s;
    for (int idx = t; idx < NPB * NCLS; idx += 512) {
        int dl = idx >> 3, kk = idx & 7;
        int d = dbase + dl;
        if (d < n) {
            float v = dinv[d] * (acc[idx] + t2w[(size_t)d * NCLS + kk]) + b2[kk];
            int g = batch[d];
            int gi = g - gb;
            if (gi < WIN) {
                atomicAdd(&wacc[gi * NCLS + kk], v);
                if (kk == 0) atomicAdd(&wcnt[gi], 1.f);
            } else {
                atomicAdd(&out[(size_t)g * NCLS + kk], v);
                if (kk == 0) atomicAdd(&cg[g], 1.f);
            }
        }
    }
    __syncthreads();
    if (t < WIN * NCLS) {
        int gg = t >> 3;
        if (wcnt[gg] > 0.f) atomicAdd(&out[(size_t)(gb + gg) * NCLS + (t & 7)], wacc[t]);
    }
    if (t < WIN && wcnt[t] > 0.f) atomicAdd(&cg[gb + t], wcnt[t]);
}

__global__ void k_div(float* __restrict__ out, const float* __restrict__ cg, int total) {
    int i = blockIdx.x * blockDim.x + threadIdx.x;
    if (i < total) out[i] /= fmaxf(cg[i / NCLS], 1.0f);
}

extern "C" void kernel_launch(void* const* d_in, const int* in_sizes, int n_in,
                              void* d_out, int out_size, void* d_ws, size_t ws_size,
                              hipStream_t stream) {
    const float* x = (const float*)d_in[0];
    const int* ei = (const int*)d_in[1];
    const int* batch = (const int*)d_in[2];
    const float* W1 = (const float*)d_in[4];
    const float* b1 = (const float*)d_in[5];
    const float* W2 = (const float*)d_in[6];
    const float* b2 = (const float*)d_in[7];

    int n = in_sizes[0] / F_IN;
    int e = in_sizes[1] / 2;
    int g = out_size / NCLS;
    const int* src = ei;
    const int* dst = ei + e;
    int nbins = (n + NPB - 1) >> BSHIFT;  // 49 for n=100000

    char* w = (char*)d_ws;
    unsigned* degc   = (unsigned*)w; w += (size_t)n * 4;
    float* dinv      = (float*)w;    w += (size_t)n * 4;
    unsigned* binCur = (unsigned*)w; w += (size_t)MAXBINS * 4;
    float* t1w       = (float*)w;    w += (size_t)n * HID * 4;
    float* hbuf      = (float*)w;    w += (size_t)n * HID * 4;
    float* t2w       = (float*)w;    w += (size_t)n * NCLS * 4;
    float* cg        = (float*)w;    w += (size_t)g * 4;
    unsigned* binbuf = (unsigned*)w; w += (size_t)MAXBINS * BCAP * 4;

    hipMemsetAsync(degc, 0, (size_t)n * 4, stream);
    hipMemsetAsync(cg, 0, (size_t)g * 4, stream);
    hipMemsetAsync(d_out, 0, (size_t)out_size * 4, stream);

    const int B = 256;
    k_bininit<<<1, MAXBINS, 0, stream>>>(binCur);
    k_binA<<<(e + TILE - 1) / TILE, 256, 0, stream>>>(src, dst, e, degc, binCur, binbuf);
    k_dinv<<<(n + B - 1) / B, B, 0, stream>>>(degc, dinv, n);
    k_gemm1<<<(n + 15) / 16, 256, 0, stream>>>(x, W1, dinv, t1w, n);
    dim3 g1(nbins, 2);
    k_agg1<<<g1, 512, 0, stream>>>(binbuf, binCur, t1w, dinv, b1, hbuf, n);
    k_gemm2<<<(n + B - 1) / B, B, 0, stream>>>(hbuf, W2, dinv, t2w, n);
    k_agg2pool<<<nbins, 512, 0, stream>>>(binbuf, binCur, t2w, dinv, b2, batch,
                                          (float*)d_out, cg, n);
    k_div<<<(out_size + B - 1) / B, B, 0, stream>>>((float*)d_out, cg, out_size);
}

// Round 6
// 710.769 us; speedup vs baseline: 2.2965x; 2.2965x over previous
//
#include <hip/hip_runtime.h>

#define F_IN 256
#define HID 16
#define NCLS 8
#define BSHIFT 10
#define BMASK ((1u << BSHIFT) - 1u)
#define NPB (1 << BSHIFT)     // 1024 nodes per bin
#define MAXBINS 128
#define BCAP 36864u           // per-bin edge capacity (mean ~32653 for uniform)
#define TILE 4096
#define SPLIT1 5
#define SPLIT2 8
#define WIN 16

typedef float f4v __attribute__((ext_vector_type(4)));

// ---------- init per-bin cursors ---------------------------------------------
__global__ void k_bininit(unsigned* __restrict__ binCur) {
    if (threadIdx.x < MAXBINS) binCur[threadIdx.x] = threadIdx.x * BCAP;
}

// ---------- pass A: degree histogram + dst-binned edge buffer ----------------
__global__ void __launch_bounds__(256) k_binA(const int* __restrict__ src,
                                              const int* __restrict__ dst, int e,
                                              unsigned* __restrict__ degc,
                                              unsigned* __restrict__ binCur,
                                              unsigned* __restrict__ binbuf) {
    __shared__ unsigned scnt[MAXBINS], lbase[MAXBINS], gbase[MAXBINS];
    __shared__ unsigned sbuf[TILE];
    __shared__ unsigned char sbin[TILE];
    int t = threadIdx.x;
    if (t < MAXBINS) scnt[t] = 0u;
    __syncthreads();
    int base = blockIdx.x * TILE;
    unsigned ent[16], rank[16];
    int ebin[16];
#pragma unroll
    for (int i = 0; i < 16; ++i) {
        int j = base + t + i * 256;
        ebin[i] = -1;
        if (j < e) {
            int d = __builtin_nontemporal_load(&dst[j]);
            int s = __builtin_nontemporal_load(&src[j]);
            atomicAdd(&degc[d], 1u);
            ent[i] = ((unsigned)s << BSHIFT) | ((unsigned)d & BMASK);
            ebin[i] = d >> BSHIFT;
            rank[i] = atomicAdd(&scnt[ebin[i]], 1u);
        }
    }
    __syncthreads();
    if (t == 0) {
        unsigned run = 0;
        for (int b = 0; b < MAXBINS; ++b) { lbase[b] = run; run += scnt[b]; }
    }
    __syncthreads();
    if (t < MAXBINS && scnt[t] > 0u) gbase[t] = atomicAdd(&binCur[t], scnt[t]);
    __syncthreads();
#pragma unroll
    for (int i = 0; i < 16; ++i)
        if (ebin[i] >= 0) {
            unsigned p = lbase[ebin[i]] + rank[i];
            sbuf[p] = ent[i];
            sbin[p] = (unsigned char)ebin[i];
        }
    __syncthreads();
    int total = e - base; if (total > TILE) total = TILE;
    for (int idx = t; idx < total; idx += 256) {
        int b = sbin[idx];
        __builtin_nontemporal_store(sbuf[idx], &binbuf[gbase[b] + ((unsigned)idx - lbase[b])]);
    }
}

// ---------- dinv -------------------------------------------------------------
__global__ void k_dinv(const unsigned* __restrict__ cnt, float* __restrict__ dinv, int n) {
    int i = blockIdx.x * blockDim.x + threadIdx.x;
    if (i < n) dinv[i] = rsqrtf((float)(cnt[i] + 1u));
}

// ---------- GEMM1: t1w[n,16] = (x @ W1) * dinv[row] --------------------------
__global__ void __launch_bounds__(256) k_gemm1(const float* __restrict__ x,
                                               const float* __restrict__ W1,
                                               const float* __restrict__ dinv,
                                               float* __restrict__ t1w, int n) {
    __shared__ float ws[HID][260];
    for (int idx = threadIdx.x; idx < F_IN * HID; idx += 256) {
        int c = idx >> 4, k = idx & 15;
        ws[k][c] = W1[idx];
    }
    __syncthreads();
    int r = blockIdx.x * 16 + (threadIdx.x >> 4);
    int k = threadIdx.x & 15;
    if (r >= n) return;
    const f4v* xr = (const f4v*)(x + (size_t)r * F_IN);
    const f4v* wr = (const f4v*)&ws[k][0];
    float acc = 0.f;
#pragma unroll 8
    for (int c4 = 0; c4 < F_IN / 4; ++c4) {
        f4v v = __builtin_nontemporal_load(&xr[c4]);
        f4v w = wr[c4];
        acc += v[0] * w[0] + v[1] * w[1] + v[2] * w[2] + v[3] * w[3];
    }
    t1w[(size_t)r * HID + k] = acc * dinv[r];
}

// ---------- conv1 aggregation: LDS scatter-add, SPLIT1 blocks per bin --------
__global__ void __launch_bounds__(512) k_agg1(const unsigned* __restrict__ binbuf,
                                              const unsigned* __restrict__ binCur,
                                              const float* __restrict__ t1w,
                                              float* __restrict__ hpart, int n) {
    __shared__ float acc[NPB * HID];  // 64 KB
    int t = threadIdx.x;
    int b = blockIdx.x, s = blockIdx.y;
    f4v z = {0.f, 0.f, 0.f, 0.f};
    for (int i = t; i < NPB * HID / 4; i += 512) ((f4v*)acc)[i] = z;
    __syncthreads();
    unsigned base = (unsigned)b * BCAP;
    unsigned cnt = binCur[b] - base;
    unsigned chunk = (cnt + SPLIT1 - 1) / SPLIT1;
    unsigned j0 = (unsigned)s * chunk;
    unsigned j1 = j0 + chunk; if (j1 > cnt) j1 = cnt;
    int k = t & 15;
    unsigned grp = t >> 4;  // 0..31
    unsigned j = j0 + grp;
    for (; j + 96 < j1; j += 128) {
        unsigned v0 = __builtin_nontemporal_load(&binbuf[base + j]);
        unsigned v1 = __builtin_nontemporal_load(&binbuf[base + j + 32]);
        unsigned v2 = __builtin_nontemporal_load(&binbuf[base + j + 64]);
        unsigned v3 = __builtin_nontemporal_load(&binbuf[base + j + 96]);
        float a0 = t1w[(size_t)(v0 >> BSHIFT) * HID + k];
        float a1 = t1w[(size_t)(v1 >> BSHIFT) * HID + k];
        float a2 = t1w[(size_t)(v2 >> BSHIFT) * HID + k];
        float a3 = t1w[(size_t)(v3 >> BSHIFT) * HID + k];
        atomicAdd(&acc[(v0 & BMASK) * HID + k], a0);
        atomicAdd(&acc[(v1 & BMASK) * HID + k], a1);
        atomicAdd(&acc[(v2 & BMASK) * HID + k], a2);
        atomicAdd(&acc[(v3 & BMASK) * HID + k], a3);
    }
    for (; j < j1; j += 32) {
        unsigned v = __builtin_nontemporal_load(&binbuf[base + j]);
        float a = t1w[(size_t)(v >> BSHIFT) * HID + k];
        atomicAdd(&acc[(v & BMASK) * HID + k], a);
    }
    __syncthreads();
    int dbase = b << BSHIFT;
    int nrows = n - dbase; if (nrows > NPB) nrows = NPB;
    f4v* po = (f4v*)(hpart + ((size_t)s * n + dbase) * HID);
    for (int i = t; i < nrows * 4; i += 512)
        __builtin_nontemporal_store(((f4v*)acc)[i], &po[i]);
}

// ---------- post conv1: sum partials + self, bias+ReLU, GEMM2 ---------------
__global__ void __launch_bounds__(256) k_post1(const float* __restrict__ hpart,
                                               const float* __restrict__ t1w,
                                               const float* __restrict__ dinv,
                                               const float* __restrict__ b1,
                                               const float* __restrict__ W2,
                                               float* __restrict__ t2w, int n) {
    __shared__ float w2s[HID * NCLS];
    __shared__ float b1s[HID];
    if (threadIdx.x < HID * NCLS) w2s[threadIdx.x] = W2[threadIdx.x];
    if (threadIdx.x < HID) b1s[threadIdx.x] = b1[threadIdx.x];
    __syncthreads();
    int i = blockIdx.x * blockDim.x + threadIdx.x;
    if (i >= n) return;
    f4v sum[4];
    const f4v* self = (const f4v*)(t1w + (size_t)i * HID);
#pragma unroll
    for (int q = 0; q < 4; ++q) sum[q] = self[q];
#pragma unroll
    for (int s = 0; s < SPLIT1; ++s) {
        const f4v* p = (const f4v*)(hpart + ((size_t)s * n + i) * HID);
#pragma unroll
        for (int q = 0; q < 4; ++q) {
            f4v v = __builtin_nontemporal_load(&p[q]);
            sum[q] += v;
        }
    }
    float di = dinv[i];
    float h[HID];
#pragma unroll
    for (int q = 0; q < 4; ++q)
#pragma unroll
        for (int r = 0; r < 4; ++r)
            h[q * 4 + r] = fmaxf(di * sum[q][r] + b1s[q * 4 + r], 0.f);
    float o[NCLS];
#pragma unroll
    for (int c = 0; c < NCLS; ++c) o[c] = 0.f;
#pragma unroll
    for (int k = 0; k < HID; ++k)
#pragma unroll
        for (int c = 0; c < NCLS; ++c) o[c] += h[k] * w2s[k * NCLS + c];
    f4v* o4 = (f4v*)(t2w + (size_t)i * NCLS);
    f4v r0 = {o[0] * di, o[1] * di, o[2] * di, o[3] * di};
    f4v r1 = {o[4] * di, o[5] * di, o[6] * di, o[7] * di};
    o4[0] = r0;
    o4[1] = r1;
}

// ---------- conv2 aggregation: LDS scatter-add, SPLIT2 blocks per bin --------
__global__ void __launch_bounds__(512) k_agg2(const unsigned* __restrict__ binbuf,
                                              const unsigned* __restrict__ binCur,
                                              const float* __restrict__ t2w,
                                              float* __restrict__ t2part, int n) {
    __shared__ float acc[NPB * NCLS];  // 32 KB
    int t = threadIdx.x;
    int b = blockIdx.x, s = blockIdx.y;
    f4v z = {0.f, 0.f, 0.f, 0.f};
    for (int i = t; i < NPB * NCLS / 4; i += 512) ((f4v*)acc)[i] = z;
    __syncthreads();
    unsigned base = (unsigned)b * BCAP;
    unsigned cnt = binCur[b] - base;
    unsigned chunk = (cnt + SPLIT2 - 1) / SPLIT2;
    unsigned j0 = (unsigned)s * chunk;
    unsigned j1 = j0 + chunk; if (j1 > cnt) j1 = cnt;
    int k = t & 7;
    unsigned grp = t >> 3;  // 0..63
    unsigned j = j0 + grp;
    for (; j + 192 < j1; j += 256) {
        unsigned v0 = __builtin_nontemporal_load(&binbuf[base + j]);
        unsigned v1 = __builtin_nontemporal_load(&binbuf[base + j + 64]);
        unsigned v2 = __builtin_nontemporal_load(&binbuf[base + j + 128]);
        unsigned v3 = __builtin_nontemporal_load(&binbuf[base + j + 192]);
        float a0 = t2w[(size_t)(v0 >> BSHIFT) * NCLS + k];
        float a1 = t2w[(size_t)(v1 >> BSHIFT) * NCLS + k];
        float a2 = t2w[(size_t)(v2 >> BSHIFT) * NCLS + k];
        float a3 = t2w[(size_t)(v3 >> BSHIFT) * NCLS + k];
        atomicAdd(&acc[(v0 & BMASK) * NCLS + k], a0);
        atomicAdd(&acc[(v1 & BMASK) * NCLS + k], a1);
        atomicAdd(&acc[(v2 & BMASK) * NCLS + k], a2);
        atomicAdd(&acc[(v3 & BMASK) * NCLS + k], a3);
    }
    for (; j < j1; j += 64) {
        unsigned v = __builtin_nontemporal_load(&binbuf[base + j]);
        float a = t2w[(size_t)(v >> BSHIFT) * NCLS + k];
        atomicAdd(&acc[(v & BMASK) * NCLS + k], a);
    }
    __syncthreads();
    int dbase = b << BSHIFT;
    int nrows = n - dbase; if (nrows > NPB) nrows = NPB;
    f4v* po = (f4v*)(t2part + ((size_t)s * n + dbase) * NCLS);
    for (int i = t; i < nrows * 2; i += 512)
        __builtin_nontemporal_store(((f4v*)acc)[i], &po[i]);
}

// ---------- post conv2: sum partials + self, bias, fused mean-pool ----------
__global__ void __launch_bounds__(512) k_post2pool(const float* __restrict__ t2part,
                                                   const float* __restrict__ t2w,
                                                   const float* __restrict__ dinv,
                                                   const float* __restrict__ b2,
                                                   const int* __restrict__ batch,
                                                   float* __restrict__ out,
                                                   float* __restrict__ cg, int n) {
    __shared__ float wacc[WIN * NCLS];
    __shared__ float wcnt[WIN];
    __shared__ int gbase_s;
    int t = threadIdx.x;
    int dbase = blockIdx.x << BSHIFT;
    if (t < WIN * NCLS) wacc[t] = 0.f;
    if (t < WIN) wcnt[t] = 0.f;
    if (t == 0) gbase_s = batch[dbase < n ? dbase : (n - 1)];
    __syncthreads();
    int gb = gbase_s;
    int k = t & 7;
    int nrows = n - dbase; if (nrows > NPB) nrows = NPB;
    for (int dl = t >> 3; dl < nrows; dl += 64) {
        int d = dbase + dl;
        float v = t2w[(size_t)d * NCLS + k];  // self
#pragma unroll
        for (int s = 0; s < SPLIT2; ++s)
            v += __builtin_nontemporal_load(&t2part[((size_t)s * n + d) * NCLS + k]);
        v = dinv[d] * v + b2[k];
        int g = batch[d];
        int gi = g - gb;
        if (gi < WIN) {
            atomicAdd(&wacc[gi * NCLS + k], v);
            if (k == 0) atomicAdd(&wcnt[gi], 1.f);
        } else {
            atomicAdd(&out[(size_t)g * NCLS + k], v);
            if (k == 0) atomicAdd(&cg[g], 1.f);
        }
    }
    __syncthreads();
    if (t < WIN * NCLS) {
        int gg = t >> 3;
        if (wcnt[gg] > 0.f) atomicAdd(&out[(size_t)(gb + gg) * NCLS + (t & 7)], wacc[t]);
    }
    if (t < WIN && wcnt[t] > 0.f) atomicAdd(&cg[gb + t], wcnt[t]);
}

__global__ void k_div(float* __restrict__ out, const float* __restrict__ cg, int total) {
    int i = blockIdx.x * blockDim.x + threadIdx.x;
    if (i < total) out[i] /= fmaxf(cg[i / NCLS], 1.0f);
}

extern "C" void kernel_launch(void* const* d_in, const int* in_sizes, int n_in,
                              void* d_out, int out_size, void* d_ws, size_t ws_size,
                              hipStream_t stream) {
    const float* x = (const float*)d_in[0];
    const int* ei = (const int*)d_in[1];
    const int* batch = (const int*)d_in[2];
    const float* W1 = (const float*)d_in[4];
    const float* b1 = (const float*)d_in[5];
    const float* W2 = (const float*)d_in[6];
    const float* b2 = (const float*)d_in[7];

    int n = in_sizes[0] / F_IN;
    int e = in_sizes[1] / 2;
    int g = out_size / NCLS;
    const int* src = ei;
    const int* dst = ei + e;
    int nbins = (n + NPB - 1) >> BSHIFT;  // 98 for n=100000

    char* w = (char*)d_ws;
    unsigned* degc   = (unsigned*)w; w += (size_t)n * 4;
    float* dinv      = (float*)w;    w += (size_t)n * 4;
    unsigned* binCur = (unsigned*)w; w += (size_t)MAXBINS * 4;
    float* t1w       = (float*)w;    w += (size_t)n * HID * 4;
    float* t2w       = (float*)w;    w += (size_t)n * NCLS * 4;
    float* cg        = (float*)w;    w += (size_t)g * 4;
    float* hpart     = (float*)w;    w += (size_t)SPLIT1 * n * HID * 4;   // 32 MB
    float* t2part    = (float*)w;    w += (size_t)SPLIT2 * n * NCLS * 4;  // 25.6 MB
    unsigned* binbuf = (unsigned*)w; w += (size_t)nbins * BCAP * 4;       // 14.5 MB

    hipMemsetAsync(degc, 0, (size_t)n * 4, stream);
    hipMemsetAsync(cg, 0, (size_t)g * 4, stream);
    hipMemsetAsync(d_out, 0, (size_t)out_size * 4, stream);

    const int B = 256;
    k_bininit<<<1, MAXBINS, 0, stream>>>(binCur);
    k_binA<<<(e + TILE - 1) / TILE, 256, 0, stream>>>(src, dst, e, degc, binCur, binbuf);
    k_dinv<<<(n + B - 1) / B, B, 0, stream>>>(degc, dinv, n);
    k_gemm1<<<(n + 15) / 16, 256, 0, stream>>>(x, W1, dinv, t1w, n);
    dim3 g1(nbins, SPLIT1);
    k_agg1<<<g1, 512, 0, stream>>>(binbuf, binCur, t1w, hpart, n);
    k_post1<<<(n + B - 1) / B, B, 0, stream>>>(hpart, t1w, dinv, b1, W2, t2w, n);
    dim3 g2(nbins, SPLIT2);
    k_agg2<<<g2, 512, 0, stream>>>(binbuf, binCur, t2w, t2part, n);
    k_post2pool<<<nbins, 512, 0, stream>>>(t2part, t2w, dinv, b2, batch,
                                           (float*)d_out, cg, n);
    k_div<<<(out_size + B - 1) / B, B, 0, stream>>>((float*)d_out, cg, out_size);
}

// Round 7
// 695.313 us; speedup vs baseline: 2.3475x; 1.0222x over previous
//
#include <hip/hip_runtime.h>

#define F_IN 256
#define HID 16
#define NCLS 8
#define BSHIFT 9
#define BMASK ((1u << BSHIFT) - 1u)
#define NPB (1 << BSHIFT)     // 512 nodes per bin
#define MAXBINS 256
#define BCAP 20480u           // per-bin edge capacity (mean ~16384, +32 sigma)
#define TILE 4096
#define SPLIT1 6
#define SPLIT2 8
#define ST1 17                // padded LDS row stride (conv1) - kills bank conflicts
#define ST2 9                 // padded LDS row stride (conv2)
#define WIN 16

typedef float f4v __attribute__((ext_vector_type(4)));

// ---------- init per-bin cursors ---------------------------------------------
__global__ void k_bininit(unsigned* __restrict__ binCur) {
    if (threadIdx.x < MAXBINS) binCur[threadIdx.x] = threadIdx.x * BCAP;
}

// ---------- pass A: degree histogram + dst-binned edge buffer ----------------
__global__ void __launch_bounds__(256) k_binA(const int* __restrict__ src,
                                              const int* __restrict__ dst, int e,
                                              unsigned* __restrict__ degc,
                                              unsigned* __restrict__ binCur,
                                              unsigned* __restrict__ binbuf) {
    __shared__ unsigned scnt[MAXBINS], lbase[MAXBINS], gbase[MAXBINS];
    __shared__ unsigned sbuf[TILE];
    __shared__ unsigned char sbin[TILE];
    int t = threadIdx.x;
    if (t < MAXBINS) scnt[t] = 0u;
    __syncthreads();
    int base = blockIdx.x * TILE;
    unsigned ent[16], rank[16];
    int ebin[16];
#pragma unroll
    for (int i = 0; i < 16; ++i) {
        int j = base + t + i * 256;
        ebin[i] = -1;
        if (j < e) {
            int d = __builtin_nontemporal_load(&dst[j]);
            int s = __builtin_nontemporal_load(&src[j]);
            atomicAdd(&degc[d], 1u);
            ent[i] = ((unsigned)s << BSHIFT) | ((unsigned)d & BMASK);
            ebin[i] = d >> BSHIFT;
            rank[i] = atomicAdd(&scnt[ebin[i]], 1u);
        }
    }
    __syncthreads();
    if (t == 0) {
        unsigned run = 0;
        for (int b = 0; b < MAXBINS; ++b) { lbase[b] = run; run += scnt[b]; }
    }
    __syncthreads();
    if (t < MAXBINS && scnt[t] > 0u) gbase[t] = atomicAdd(&binCur[t], scnt[t]);
    __syncthreads();
#pragma unroll
    for (int i = 0; i < 16; ++i)
        if (ebin[i] >= 0) {
            unsigned p = lbase[ebin[i]] + rank[i];
            sbuf[p] = ent[i];
            sbin[p] = (unsigned char)ebin[i];
        }
    __syncthreads();
    int total = e - base; if (total > TILE) total = TILE;
    for (int idx = t; idx < total; idx += 256) {
        int b = sbin[idx];
        __builtin_nontemporal_store(sbuf[idx], &binbuf[gbase[b] + ((unsigned)idx - lbase[b])]);
    }
}

// ---------- GEMM1: t1w[n,16] = (x @ W1) * rsqrt(deg+1) -----------------------
__global__ void __launch_bounds__(256) k_gemm1(const float* __restrict__ x,
                                               const float* __restrict__ W1,
                                               const unsigned* __restrict__ degc,
                                               float* __restrict__ t1w, int n) {
    __shared__ float ws[HID][260];
    for (int idx = threadIdx.x; idx < F_IN * HID; idx += 256) {
        int c = idx >> 4, k = idx & 15;
        ws[k][c] = W1[idx];
    }
    __syncthreads();
    int r = blockIdx.x * 16 + (threadIdx.x >> 4);
    int k = threadIdx.x & 15;
    if (r >= n) return;
    const f4v* xr = (const f4v*)(x + (size_t)r * F_IN);
    const f4v* wr = (const f4v*)&ws[k][0];
    float acc = 0.f;
#pragma unroll 8
    for (int c4 = 0; c4 < F_IN / 4; ++c4) {
        f4v v = __builtin_nontemporal_load(&xr[c4]);
        f4v w = wr[c4];
        acc += v[0] * w[0] + v[1] * w[1] + v[2] * w[2] + v[3] * w[3];
    }
    t1w[(size_t)r * HID + k] = acc * rsqrtf((float)(degc[r] + 1u));
}

// ---------- conv1 aggregation: LDS scatter-add, 4 lanes x float4 per edge ----
__global__ void __launch_bounds__(512) k_agg1(const unsigned* __restrict__ binbuf,
                                              const unsigned* __restrict__ binCur,
                                              const float* __restrict__ t1w,
                                              float* __restrict__ hpart, int n) {
    __shared__ float acc[NPB * ST1];  // 34.8 KB -> 4 blocks/CU
    int t = threadIdx.x;
    int b = blockIdx.x, s = blockIdx.y;
    f4v z = {0.f, 0.f, 0.f, 0.f};
    for (int i = t; i < NPB * ST1 / 4; i += 512) ((f4v*)acc)[i] = z;
    __syncthreads();
    unsigned base = (unsigned)b * BCAP;
    unsigned cnt = binCur[b] - base;
    unsigned chunk = (cnt + SPLIT1 - 1) / SPLIT1;
    unsigned j0 = (unsigned)s * chunk;
    unsigned j1 = j0 + chunk; if (j1 > cnt) j1 = cnt;
    int sub4 = (t & 3) * 4;
    const unsigned STR = 128;  // 512 threads / 4 lanes per edge
    unsigned j = j0 + (t >> 2);
    for (; j + 3 * STR < j1; j += 4 * STR) {
        unsigned v0 = __builtin_nontemporal_load(&binbuf[base + j]);
        unsigned v1 = __builtin_nontemporal_load(&binbuf[base + j + STR]);
        unsigned v2 = __builtin_nontemporal_load(&binbuf[base + j + 2 * STR]);
        unsigned v3 = __builtin_nontemporal_load(&binbuf[base + j + 3 * STR]);
        f4v a0 = *(const f4v*)&t1w[(size_t)(v0 >> BSHIFT) * HID + sub4];
        f4v a1 = *(const f4v*)&t1w[(size_t)(v1 >> BSHIFT) * HID + sub4];
        f4v a2 = *(const f4v*)&t1w[(size_t)(v2 >> BSHIFT) * HID + sub4];
        f4v a3 = *(const f4v*)&t1w[(size_t)(v3 >> BSHIFT) * HID + sub4];
        int n0 = (int)(v0 & BMASK) * ST1 + sub4;
        int n1 = (int)(v1 & BMASK) * ST1 + sub4;
        int n2 = (int)(v2 & BMASK) * ST1 + sub4;
        int n3 = (int)(v3 & BMASK) * ST1 + sub4;
#pragma unroll
        for (int r = 0; r < 4; ++r) atomicAdd(&acc[n0 + r], a0[r]);
#pragma unroll
        for (int r = 0; r < 4; ++r) atomicAdd(&acc[n1 + r], a1[r]);
#pragma unroll
        for (int r = 0; r < 4; ++r) atomicAdd(&acc[n2 + r], a2[r]);
#pragma unroll
        for (int r = 0; r < 4; ++r) atomicAdd(&acc[n3 + r], a3[r]);
    }
    for (; j < j1; j += STR) {
        unsigned v = __builtin_nontemporal_load(&binbuf[base + j]);
        f4v a = *(const f4v*)&t1w[(size_t)(v >> BSHIFT) * HID + sub4];
        int n0 = (int)(v & BMASK) * ST1 + sub4;
#pragma unroll
        for (int r = 0; r < 4; ++r) atomicAdd(&acc[n0 + r], a[r]);
    }
    __syncthreads();
    int dbase = b << BSHIFT;
    int nrows = n - dbase; if (nrows > NPB) nrows = NPB;
    float* po = hpart + ((size_t)s * n + dbase) * HID;
    for (int idx = t; idx < nrows * HID; idx += 512) {
        int dl = idx >> 4, f = idx & 15;
        __builtin_nontemporal_store(acc[dl * ST1 + f], &po[idx]);
    }
}

// ---------- post conv1: sum partials + self, bias+ReLU, GEMM2 ----------------
__global__ void __launch_bounds__(256) k_post1(const float* __restrict__ hpart,
                                               const float* __restrict__ t1w,
                                               const unsigned* __restrict__ degc,
                                               const float* __restrict__ b1,
                                               const float* __restrict__ W2,
                                               float* __restrict__ t2w, int n) {
    __shared__ float w2s[HID * NCLS];
    __shared__ float b1s[HID];
    if (threadIdx.x < HID * NCLS) w2s[threadIdx.x] = W2[threadIdx.x];
    if (threadIdx.x < HID) b1s[threadIdx.x] = b1[threadIdx.x];
    __syncthreads();
    int i = blockIdx.x * blockDim.x + threadIdx.x;
    if (i >= n) return;
    f4v sum[4];
    const f4v* self = (const f4v*)(t1w + (size_t)i * HID);
#pragma unroll
    for (int q = 0; q < 4; ++q) sum[q] = self[q];
#pragma unroll
    for (int s = 0; s < SPLIT1; ++s) {
        const f4v* p = (const f4v*)(hpart + ((size_t)s * n + i) * HID);
#pragma unroll
        for (int q = 0; q < 4; ++q) {
            f4v v = __builtin_nontemporal_load(&p[q]);
            sum[q] += v;
        }
    }
    float di = rsqrtf((float)(degc[i] + 1u));
    float h[HID];
#pragma unroll
    for (int q = 0; q < 4; ++q)
#pragma unroll
        for (int r = 0; r < 4; ++r)
            h[q * 4 + r] = fmaxf(di * sum[q][r] + b1s[q * 4 + r], 0.f);
    float o[NCLS];
#pragma unroll
    for (int c = 0; c < NCLS; ++c) o[c] = 0.f;
#pragma unroll
    for (int k = 0; k < HID; ++k)
#pragma unroll
        for (int c = 0; c < NCLS; ++c) o[c] += h[k] * w2s[k * NCLS + c];
    f4v* o4 = (f4v*)(t2w + (size_t)i * NCLS);
    f4v r0 = {o[0] * di, o[1] * di, o[2] * di, o[3] * di};
    f4v r1 = {o[4] * di, o[5] * di, o[6] * di, o[7] * di};
    o4[0] = r0;
    o4[1] = r1;
}

// ---------- conv2 aggregation: LDS scatter-add, 2 lanes x float4 per edge ----
__global__ void __launch_bounds__(256) k_agg2(const unsigned* __restrict__ binbuf,
                                              const unsigned* __restrict__ binCur,
                                              const float* __restrict__ t2w,
                                              float* __restrict__ t2part, int n) {
    __shared__ float acc[NPB * ST2];  // 18 KB -> 8 blocks/CU
    int t = threadIdx.x;
    int b = blockIdx.x, s = blockIdx.y;
    f4v z = {0.f, 0.f, 0.f, 0.f};
    for (int i = t; i < NPB * ST2 / 4; i += 256) ((f4v*)acc)[i] = z;
    __syncthreads();
    unsigned base = (unsigned)b * BCAP;
    unsigned cnt = binCur[b] - base;
    unsigned chunk = (cnt + SPLIT2 - 1) / SPLIT2;
    unsigned j0 = (unsigned)s * chunk;
    unsigned j1 = j0 + chunk; if (j1 > cnt) j1 = cnt;
    int sub4 = (t & 1) * 4;
    const unsigned STR = 128;  // 256 threads / 2 lanes per edge
    unsigned j = j0 + (t >> 1);
    for (; j + 3 * STR < j1; j += 4 * STR) {
        unsigned v0 = __builtin_nontemporal_load(&binbuf[base + j]);
        unsigned v1 = __builtin_nontemporal_load(&binbuf[base + j + STR]);
        unsigned v2 = __builtin_nontemporal_load(&binbuf[base + j + 2 * STR]);
        unsigned v3 = __builtin_nontemporal_load(&binbuf[base + j + 3 * STR]);
        f4v a0 = *(const f4v*)&t2w[(size_t)(v0 >> BSHIFT) * NCLS + sub4];
        f4v a1 = *(const f4v*)&t2w[(size_t)(v1 >> BSHIFT) * NCLS + sub4];
        f4v a2 = *(const f4v*)&t2w[(size_t)(v2 >> BSHIFT) * NCLS + sub4];
        f4v a3 = *(const f4v*)&t2w[(size_t)(v3 >> BSHIFT) * NCLS + sub4];
        int n0 = (int)(v0 & BMASK) * ST2 + sub4;
        int n1 = (int)(v1 & BMASK) * ST2 + sub4;
        int n2 = (int)(v2 & BMASK) * ST2 + sub4;
        int n3 = (int)(v3 & BMASK) * ST2 + sub4;
#pragma unroll
        for (int r = 0; r < 4; ++r) atomicAdd(&acc[n0 + r], a0[r]);
#pragma unroll
        for (int r = 0; r < 4; ++r) atomicAdd(&acc[n1 + r], a1[r]);
#pragma unroll
        for (int r = 0; r < 4; ++r) atomicAdd(&acc[n2 + r], a2[r]);
#pragma unroll
        for (int r = 0; r < 4; ++r) atomicAdd(&acc[n3 + r], a3[r]);
    }
    for (; j < j1; j += STR) {
        unsigned v = __builtin_nontemporal_load(&binbuf[base + j]);
        f4v a = *(const f4v*)&t2w[(size_t)(v >> BSHIFT) * NCLS + sub4];
        int n0 = (int)(v & BMASK) * ST2 + sub4;
#pragma unroll
        for (int r = 0; r < 4; ++r) atomicAdd(&acc[n0 + r], a[r]);
    }
    __syncthreads();
    int dbase = b << BSHIFT;
    int nrows = n - dbase; if (nrows > NPB) nrows = NPB;
    float* po = t2part + ((size_t)s * n + dbase) * NCLS;
    for (int idx = t; idx < nrows * NCLS; idx += 256) {
        int dl = idx >> 3, f = idx & 7;
        __builtin_nontemporal_store(acc[dl * ST2 + f], &po[idx]);
    }
}

// ---------- post conv2: sum partials + self, bias, fused mean-pool -----------
__global__ void __launch_bounds__(512) k_post2pool(const float* __restrict__ t2part,
                                                   const float* __restrict__ t2w,
                                                   const unsigned* __restrict__ degc,
                                                   const float* __restrict__ b2,
                                                   const int* __restrict__ batch,
                                                   float* __restrict__ out,
                                                   float* __restrict__ cg, int n) {
    __shared__ float wacc[WIN * NCLS];
    __shared__ float wcnt[WIN];
    __shared__ int gbase_s;
    int t = threadIdx.x;
    int dbase = blockIdx.x << BSHIFT;
    if (t < WIN * NCLS) wacc[t] = 0.f;
    if (t < WIN) wcnt[t] = 0.f;
    if (t == 0) gbase_s = batch[dbase < n ? dbase : (n - 1)];
    __syncthreads();
    int gb = gbase_s;
    int k = t & 7;
    int nrows = n - dbase; if (nrows > NPB) nrows = NPB;
    for (int dl = t >> 3; dl < nrows; dl += 64) {
        int d = dbase + dl;
        float v = t2w[(size_t)d * NCLS + k];  // self
#pragma unroll
        for (int s = 0; s < SPLIT2; ++s)
            v += __builtin_nontemporal_load(&t2part[((size_t)s * n + d) * NCLS + k]);
        v = rsqrtf((float)(degc[d] + 1u)) * v + b2[k];
        int g = batch[d];
        int gi = g - gb;
        if (gi < WIN) {
            atomicAdd(&wacc[gi * NCLS + k], v);
            if (k == 0) atomicAdd(&wcnt[gi], 1.f);
        } else {
            atomicAdd(&out[(size_t)g * NCLS + k], v);
            if (k == 0) atomicAdd(&cg[g], 1.f);
        }
    }
    __syncthreads();
    if (t < WIN * NCLS) {
        int gg = t >> 3;
        if (wcnt[gg] > 0.f) atomicAdd(&out[(size_t)(gb + gg) * NCLS + (t & 7)], wacc[t]);
    }
    if (t < WIN && wcnt[t] > 0.f) atomicAdd(&cg[gb + t], wcnt[t]);
}

__global__ void k_div(float* __restrict__ out, const float* __restrict__ cg, int total) {
    int i = blockIdx.x * blockDim.x + threadIdx.x;
    if (i < total) out[i] /= fmaxf(cg[i / NCLS], 1.0f);
}

extern "C" void kernel_launch(void* const* d_in, const int* in_sizes, int n_in,
                              void* d_out, int out_size, void* d_ws, size_t ws_size,
                              hipStream_t stream) {
    const float* x = (const float*)d_in[0];
    const int* ei = (const int*)d_in[1];
    const int* batch = (const int*)d_in[2];
    const float* W1 = (const float*)d_in[4];
    const float* b1 = (const float*)d_in[5];
    const float* W2 = (const float*)d_in[6];
    const float* b2 = (const float*)d_in[7];

    int n = in_sizes[0] / F_IN;
    int e = in_sizes[1] / 2;
    int g = out_size / NCLS;
    const int* src = ei;
    const int* dst = ei + e;
    int nbins = (n + NPB - 1) >> BSHIFT;  // 196 for n=100000

    char* w = (char*)d_ws;
    unsigned* degc   = (unsigned*)w; w += (size_t)n * 4;
    unsigned* binCur = (unsigned*)w; w += (size_t)MAXBINS * 4;
    float* t1w       = (float*)w;    w += (size_t)n * HID * 4;
    float* t2w       = (float*)w;    w += (size_t)n * NCLS * 4;
    float* cg        = (float*)w;    w += (size_t)g * 4;
    float* hpart     = (float*)w;    w += (size_t)SPLIT1 * n * HID * 4;   // 38.4 MB
    float* t2part    = (float*)w;    w += (size_t)SPLIT2 * n * NCLS * 4;  // 25.6 MB
    unsigned* binbuf = (unsigned*)w; w += (size_t)nbins * BCAP * 4;       // 16.1 MB

    hipMemsetAsync(degc, 0, (size_t)n * 4, stream);
    hipMemsetAsync(cg, 0, (size_t)g * 4, stream);
    hipMemsetAsync(d_out, 0, (size_t)out_size * 4, stream);

    const int B = 256;
    k_bininit<<<1, MAXBINS, 0, stream>>>(binCur);
    k_binA<<<(e + TILE - 1) / TILE, 256, 0, stream>>>(src, dst, e, degc, binCur, binbuf);
    k_gemm1<<<(n + 15) / 16, 256, 0, stream>>>(x, W1, degc, t1w, n);
    dim3 g1(nbins, SPLIT1);
    k_agg1<<<g1, 512, 0, stream>>>(binbuf, binCur, t1w, hpart, n);
    k_post1<<<(n + B - 1) / B, B, 0, stream>>>(hpart, t1w, degc, b1, W2, t2w, n);
    dim3 g2(nbins, SPLIT2);
    k_agg2<<<g2, 256, 0, stream>>>(binbuf, binCur, t2w, t2part, n);
    k_post2pool<<<nbins, 512, 0, stream>>>(t2part, t2w, degc, b2, batch,
                                           (float*)d_out, cg, n);
    k_div<<<(out_size + B - 1) / B, B, 0, stream>>>((float*)d_out, cg, out_size);
}